// Round 1
// baseline (280.892 us; speedup 1.0000x reference)
//
#include <hip/hip_runtime.h>
#include <hip/hip_bf16.h>
#include <stdint.h>

// Problem constants (EuclideanDeconf): x[B,D] fp32, W[C,D] fp32, out[B,C] fp32
#define B_ROWS 16384
#define D_DIM  1024
#define C_DIM  2048

#define BM 128
#define BN 128
#define BK 64

typedef short bf16x8 __attribute__((ext_vector_type(8)));   // 8 bf16 = 4 VGPRs
typedef float f32x4  __attribute__((ext_vector_type(4)));

// ---------------------------------------------------------------------------
// Pass 1: fp32 -> bf16 conversion + fp32 row sum-of-squares / D.
// One block per row (D=1024 = 256 float4 = 1 float4/thread).
// ---------------------------------------------------------------------------
__global__ __launch_bounds__(256) void cvt_norm(const float* __restrict__ src,
                                                ushort* __restrict__ dst,
                                                float* __restrict__ norm) {
    const int row = blockIdx.x;
    const int t   = threadIdx.x;
    const float4 v = ((const float4*)(src + (size_t)row * D_DIM))[t];
    float s = v.x * v.x + v.y * v.y + v.z * v.z + v.w * v.w;

    ushort4 u;
    __hip_bfloat16 h;
    h = __float2bfloat16(v.x); u.x = *(const ushort*)&h;
    h = __float2bfloat16(v.y); u.y = *(const ushort*)&h;
    h = __float2bfloat16(v.z); u.z = *(const ushort*)&h;
    h = __float2bfloat16(v.w); u.w = *(const ushort*)&h;
    ((ushort4*)(dst + (size_t)row * D_DIM))[t] = u;

    // wave=64 shuffle reduce, then 4-wave LDS combine
    #pragma unroll
    for (int o = 32; o > 0; o >>= 1) s += __shfl_down(s, o, 64);
    __shared__ float red[4];
    if ((t & 63) == 0) red[t >> 6] = s;
    __syncthreads();
    if (t == 0)
        norm[row] = (red[0] + red[1] + red[2] + red[3]) * (1.0f / (float)D_DIM);
}

// ---------------------------------------------------------------------------
// Pass 2: bf16 MFMA GEMM (A = xb [B,D], B = wb [C,D], both K-contiguous)
// 128x128 block tile, BK=64, 256 threads = 4 waves in 2x2 (64x64 each),
// 16x16x32 bf16 MFMA, global_load_lds width-16 staging (m97 structure).
// Epilogue: out = acc*(2/D) - x2[row] - w2[col].
// ---------------------------------------------------------------------------
__global__ __launch_bounds__(256) void gemm_epilogue(
        const ushort* __restrict__ xb, const ushort* __restrict__ wb,
        const float* __restrict__ x2, const float* __restrict__ w2,
        float* __restrict__ out) {
    // NOTE: no padding — global_load_lds lands lane i at wave-uniform base + i*16B,
    // so LDS layout must be exactly linear [row][BK].
    __shared__ ushort As[BM * BK];   // 16 KB
    __shared__ ushort Bs[BN * BK];   // 16 KB

    const int tid  = threadIdx.x;
    const int lane = tid & 63;
    const int bx   = blockIdx.x;
    const int nTiles = C_DIM / BN;                 // 16 consecutive blocks share an A tile
    const int mBase  = (bx / nTiles) * BM;
    const int nBase  = (bx % nTiles) * BN;

    const int waveM = ((tid >> 6) >> 1) * 64;      // 2x2 wave grid
    const int waveN = ((tid >> 6) & 1) * 64;

    f32x4 acc[4][4];
    #pragma unroll
    for (int mi = 0; mi < 4; ++mi)
        #pragma unroll
        for (int ni = 0; ni < 4; ++ni)
            acc[mi][ni] = (f32x4){0.f, 0.f, 0.f, 0.f};

    const ushort* aG = xb + (size_t)mBase * D_DIM;
    const ushort* bG = wb + (size_t)nBase * D_DIM;

    const int rsel = lane & 15;      // m (A) / n (B) within 16x16 tile
    const int quad = lane >> 4;      // k-quad: 8 bf16 each

    for (int kt = 0; kt < D_DIM; kt += BK) {
        // ---- stage A and B tiles: 16 KB each, 4 rounds of 256 lanes x 16 B ----
        #pragma unroll
        for (int j = 0; j < 4; ++j) {
            const int c    = j * 256 + tid;        // 16B-chunk index, linear in LDS
            const int row  = c >> 3;               // 8 chunks per 64-elem row
            const int koff = (c & 7) * 8;
            const int ldsb = (j * 256 + (tid & 192)) * 8;   // wave-uniform base (elems)
            __builtin_amdgcn_global_load_lds(
                (const __attribute__((address_space(1))) void*)(aG + (size_t)row * D_DIM + kt + koff),
                (__attribute__((address_space(3))) void*)(As + ldsb), 16, 0, 0);
            __builtin_amdgcn_global_load_lds(
                (const __attribute__((address_space(1))) void*)(bG + (size_t)row * D_DIM + kt + koff),
                (__attribute__((address_space(3))) void*)(Bs + ldsb), 16, 0, 0);
        }
        __syncthreads();   // compiler emits vmcnt(0) drain before s_barrier

        // ---- compute: 2 k-steps x 16 MFMAs ----
        #pragma unroll
        for (int ks = 0; ks < 2; ++ks) {
            const int k0 = ks * 32;
            bf16x8 a[4], b[4];
            #pragma unroll
            for (int mi = 0; mi < 4; ++mi)
                a[mi] = *(const bf16x8*)(As + (waveM + mi * 16 + rsel) * BK + k0 + quad * 8);
            #pragma unroll
            for (int ni = 0; ni < 4; ++ni)
                b[ni] = *(const bf16x8*)(Bs + (waveN + ni * 16 + rsel) * BK + k0 + quad * 8);
            #pragma unroll
            for (int mi = 0; mi < 4; ++mi)
                #pragma unroll
                for (int ni = 0; ni < 4; ++ni)
                    acc[mi][ni] = __builtin_amdgcn_mfma_f32_16x16x32_bf16(
                        a[mi], b[ni], acc[mi][ni], 0, 0, 0);
        }
        __syncthreads();   // protect LDS from next iteration's staging
    }

    // ---- epilogue: C/D layout col=lane&15, row=(lane>>4)*4+reg (m89-verified) ----
    const float scale = 2.0f / (float)D_DIM;
    const int col0 = nBase + waveN + rsel;
    const int row0 = mBase + waveM + quad * 4;

    float x2r[4][4];
    #pragma unroll
    for (int mi = 0; mi < 4; ++mi)
        #pragma unroll
        for (int r = 0; r < 4; ++r)
            x2r[mi][r] = x2[row0 + mi * 16 + r];

    #pragma unroll
    for (int ni = 0; ni < 4; ++ni) {
        const int c   = col0 + ni * 16;
        const float wc = w2[c];
        #pragma unroll
        for (int mi = 0; mi < 4; ++mi) {
            #pragma unroll
            for (int r = 0; r < 4; ++r) {
                const int rr = row0 + mi * 16 + r;
                out[(size_t)rr * C_DIM + c] = acc[mi][ni][r] * scale - x2r[mi][r] - wc;
            }
        }
    }
}

// ---------------------------------------------------------------------------
extern "C" void kernel_launch(void* const* d_in, const int* in_sizes, int n_in,
                              void* d_out, int out_size, void* d_ws, size_t ws_size,
                              hipStream_t stream) {
    const float* x = (const float*)d_in[0];   // [B, D] fp32
    const float* W = (const float*)d_in[1];   // [C, D] fp32
    float* out = (float*)d_out;               // [B, C] fp32

    // workspace layout: xb (32 MB bf16) | wb (4 MB bf16) | x2 (64 KB) | w2 (8 KB)
    char* ws = (char*)d_ws;
    ushort* xb = (ushort*)ws;
    ushort* wb = (ushort*)(ws + (size_t)B_ROWS * D_DIM * sizeof(ushort));
    float*  x2 = (float*)(ws + (size_t)(B_ROWS + C_DIM) * D_DIM * sizeof(ushort));
    float*  w2 = x2 + B_ROWS;

    cvt_norm<<<B_ROWS, 256, 0, stream>>>(x, xb, x2);
    cvt_norm<<<C_DIM, 256, 0, stream>>>(W, wb, w2);

    gemm_epilogue<<<(B_ROWS / BM) * (C_DIM / BN), 256, 0, stream>>>(xb, wb, x2, w2, out);
}

// Round 2
// 267.307 us; speedup vs baseline: 1.0508x; 1.0508x over previous
//
#include <hip/hip_runtime.h>
#include <hip/hip_bf16.h>
#include <stdint.h>

// Problem constants (EuclideanDeconf): x[B,D] fp32, W[C,D] fp32, out[B,C] fp32
#define B_ROWS 16384
#define D_DIM  1024
#define C_DIM  2048

#define BM 128
#define BN 128
#define BK 64

typedef short bf16x8 __attribute__((ext_vector_type(8)));   // 8 bf16 = 4 VGPRs
typedef float f32x4  __attribute__((ext_vector_type(4)));

// ---------------------------------------------------------------------------
// Pass 1 (single launch): fp32 -> bf16 conversion + fp32 row sum(x^2)/D.
// Blocks [0, B) handle x; blocks [B, B+C) handle W.
// ---------------------------------------------------------------------------
__global__ __launch_bounds__(256) void cvt_norm_all(
        const float* __restrict__ x, const float* __restrict__ W,
        ushort* __restrict__ xb, ushort* __restrict__ wb,
        float* __restrict__ x2, float* __restrict__ w2) {
    const int blk = blockIdx.x;
    const float* src; ushort* dst; float* norm; int row;
    if (blk < B_ROWS) { src = x; dst = xb; norm = x2; row = blk; }
    else              { src = W; dst = wb; norm = w2; row = blk - B_ROWS; }

    const int t = threadIdx.x;
    const float4 v = ((const float4*)(src + (size_t)row * D_DIM))[t];
    float s = v.x * v.x + v.y * v.y + v.z * v.z + v.w * v.w;

    ushort4 u;
    __hip_bfloat16 h;
    h = __float2bfloat16(v.x); u.x = *(const ushort*)&h;
    h = __float2bfloat16(v.y); u.y = *(const ushort*)&h;
    h = __float2bfloat16(v.z); u.z = *(const ushort*)&h;
    h = __float2bfloat16(v.w); u.w = *(const ushort*)&h;
    ((ushort4*)(dst + (size_t)row * D_DIM))[t] = u;

    #pragma unroll
    for (int o = 32; o > 0; o >>= 1) s += __shfl_down(s, o, 64);
    __shared__ float red[4];
    if ((t & 63) == 0) red[t >> 6] = s;
    __syncthreads();
    if (t == 0)
        norm[row] = (red[0] + red[1] + red[2] + red[3]) * (1.0f / (float)D_DIM);
}

// ---------------------------------------------------------------------------
// Pass 2: bf16 MFMA GEMM, 128x128 tile, BK=64, 4 waves (2x2 of 64x64).
// LDS layout is XOR-swizzled in 16B k-chunks: chunk (row, kc) lives at
// physical chunk (row, kc ^ (row&7)). The global_load_lds DMA writes lanes
// linearly, so the swizzle is applied on the global SOURCE index per lane;
// reads apply the same XOR. This spreads fragment reads uniformly over all
// 8 bank granules (was: 16-way aliasing on a 4-bank granule, 2.5e7 conflict
// cycles in R1).
// Block remap: XCD i (bx%8, dispatch round-robin) gets a contiguous slab of
// 16 m-tiles x all 16 n-tiles for A-tile L2 locality.
// Epilogue: out = acc*(2/D) - x2[row] - w2[col].
// ---------------------------------------------------------------------------
__global__ __launch_bounds__(256) void gemm_epilogue(
        const ushort* __restrict__ xb, const ushort* __restrict__ wb,
        const float* __restrict__ x2, const float* __restrict__ w2,
        float* __restrict__ out) {
    __shared__ ushort As[BM * BK];   // 16 KB
    __shared__ ushort Bs[BN * BK];   // 16 KB

    const int tid  = threadIdx.x;
    const int lane = tid & 63;
    const int nT   = C_DIM / BN;                  // 16
    const int per  = (B_ROWS / BM) * nT / 8;      // 256 blocks per XCD slab
    const int wid  = (blockIdx.x & 7) * per + (blockIdx.x >> 3);
    const int mBase = (wid / nT) * BM;
    const int nBase = (wid % nT) * BN;

    const int waveM = ((tid >> 6) >> 1) * 64;     // 2x2 wave grid
    const int waveN = ((tid >> 6) & 1) * 64;

    f32x4 acc[4][4];
    #pragma unroll
    for (int mi = 0; mi < 4; ++mi)
        #pragma unroll
        for (int ni = 0; ni < 4; ++ni)
            acc[mi][ni] = (f32x4){0.f, 0.f, 0.f, 0.f};

    const ushort* aG = xb + (size_t)mBase * D_DIM;
    const ushort* bG = wb + (size_t)nBase * D_DIM;

    const int rsel = lane & 15;      // m (A) / n (B) within 16x16 tile
    const int quad = lane >> 4;      // k-quad: 8 bf16 each
    const int rk   = rsel & 7;       // row component of the XOR swizzle

    for (int kt = 0; kt < D_DIM; kt += BK) {
        // ---- stage A/B tiles: 4 rounds x 256 lanes x 16B, swizzled source ----
        #pragma unroll
        for (int j = 0; j < 4; ++j) {
            const int c    = j * 256 + tid;        // linear 16B-chunk in LDS
            const int row  = c >> 3;               // 8 chunks per 64-elem row
            const int ksrc = (c & 7) ^ (row & 7);  // swizzled source k-chunk
            const int ldsb = (j * 256 + (tid & 192)) * 8;   // wave-uniform base
            __builtin_amdgcn_global_load_lds(
                (const __attribute__((address_space(1))) void*)(aG + (size_t)row * D_DIM + kt + ksrc * 8),
                (__attribute__((address_space(3))) void*)(As + ldsb), 16, 0, 0);
            __builtin_amdgcn_global_load_lds(
                (const __attribute__((address_space(1))) void*)(bG + (size_t)row * D_DIM + kt + ksrc * 8),
                (__attribute__((address_space(3))) void*)(Bs + ldsb), 16, 0, 0);
        }
        __syncthreads();

        // ---- compute: 2 k-steps x 16 MFMAs ----
        #pragma unroll
        for (int ks = 0; ks < 2; ++ks) {
            const int kph = ((ks * 4 + quad) ^ rk) * 8;   // swizzled k offset (elems)
            bf16x8 a[4], b[4];
            #pragma unroll
            for (int mi = 0; mi < 4; ++mi)
                a[mi] = *(const bf16x8*)(As + (waveM + mi * 16 + rsel) * BK + kph);
            #pragma unroll
            for (int ni = 0; ni < 4; ++ni)
                b[ni] = *(const bf16x8*)(Bs + (waveN + ni * 16 + rsel) * BK + kph);
            #pragma unroll
            for (int mi = 0; mi < 4; ++mi)
                #pragma unroll
                for (int ni = 0; ni < 4; ++ni)
                    acc[mi][ni] = __builtin_amdgcn_mfma_f32_16x16x32_bf16(
                        a[mi], b[ni], acc[mi][ni], 0, 0, 0);
        }
        __syncthreads();
    }

    // ---- epilogue: C/D layout col=lane&15, row=(lane>>4)*4+reg (m89) ----
    const float scale = 2.0f / (float)D_DIM;
    const int col0 = nBase + waveN + rsel;
    const int row0 = mBase + waveM + quad * 4;

    float x2r[4][4];
    #pragma unroll
    for (int mi = 0; mi < 4; ++mi)
        #pragma unroll
        for (int r = 0; r < 4; ++r)
            x2r[mi][r] = x2[row0 + mi * 16 + r];

    #pragma unroll
    for (int ni = 0; ni < 4; ++ni) {
        const int c = col0 + ni * 16;
        const float wc = w2[c];
        #pragma unroll
        for (int mi = 0; mi < 4; ++mi) {
            #pragma unroll
            for (int r = 0; r < 4; ++r) {
                const int rr = row0 + mi * 16 + r;
                out[(size_t)rr * C_DIM + c] = acc[mi][ni][r] * scale - x2r[mi][r] - wc;
            }
        }
    }
}

// ---------------------------------------------------------------------------
extern "C" void kernel_launch(void* const* d_in, const int* in_sizes, int n_in,
                              void* d_out, int out_size, void* d_ws, size_t ws_size,
                              hipStream_t stream) {
    const float* x = (const float*)d_in[0];   // [B, D] fp32
    const float* W = (const float*)d_in[1];   // [C, D] fp32
    float* out = (float*)d_out;               // [B, C] fp32

    // workspace layout: xb (32 MB bf16) | wb (4 MB bf16) | x2 (64 KB) | w2 (8 KB)
    char* ws = (char*)d_ws;
    ushort* xb = (ushort*)ws;
    ushort* wb = (ushort*)(ws + (size_t)B_ROWS * D_DIM * sizeof(ushort));
    float*  x2 = (float*)(ws + (size_t)(B_ROWS + C_DIM) * D_DIM * sizeof(ushort));
    float*  w2 = x2 + B_ROWS;

    cvt_norm_all<<<B_ROWS + C_DIM, 256, 0, stream>>>(x, W, xb, wb, x2, w2);
    gemm_epilogue<<<(B_ROWS / BM) * (C_DIM / BN), 256, 0, stream>>>(xb, wb, x2, w2, out);
}